// Round 2
// baseline (226.547 us; speedup 1.0000x reference)
//
#include <hip/hip_runtime.h>

// LTFGW semi-relaxed FGW — round 16: persistent-grid srfgw (isolated change).
// Gap postmortem: gcost v5 (DPP serial) and v6 (LDS SGEMM) give identical
//   ~60 us gap -> gap is fixed per-iteration overhead (2nd launch + harness
//   reset dispatches), NOT gcost duration. Both v5/v6 are <10 us issue-bound.
//   => only lever is srfgw itself.
// srfgw r13 analysis: VALU-issue-bound (VALUBusy 78%), Occupancy 60% despite
//   resources allowing 4 blocks/CU = 100%: grid 3432 over 1024-resident
//   capacity = 3.35 rounds, last round 35% full + per-round drain.
// r16: persistent grid = exactly 1024 blocks (4/CU by 36 VGPR, 147KB/CU LDS,
//   launch_bounds(512,4)); each block grid-strides over 3432 (nb,kb) tiles.
//   Tile seam needs no extra barrier: all LDS reads of setup structures end
//   before final-iter barrier(2), which separates tiles. Per-tile math
//   byte-identical to r13.
// gcost: v6 verbatim (LDS-staged 64x32 SGEMM, conflict-free, ~6 us).

#define NN    6000
#define DEG   16
#define MM    17
#define NTPL  16
#define MT    10
#define NF    128
#define NITER 10
#define KPB   4
#define NPB   7
#define BS    512
#define RS    12            // padded T row stride (floats)
#define LOG2E 1.44269504088896340736f

#define NBTILES ((NN + NPB - 1) / NPB)          // 858
#define NTILES  (NBTILES * (NTPL / KPB))        // 3432
#define PGRID   1024                            // persistent blocks (4/CU)

__device__ __forceinline__ float fexp2(float x) { return __builtin_amdgcn_exp2f(x); }
__device__ __forceinline__ float frcp(float x)  { return __builtin_amdgcn_rcpf(x); }

// ---------------- gcost v6: tiled SGEMM G[v,kt] = mcoefl*(||F2[kt]||^2 - 2 x[v].F2[kt])
#define GBN  64             // nodes per block
#define GBK  32             // kts per block
#define GPAD 132            // LDS row stride in floats (132*4B, 16B-aligned rows)

__global__ __launch_bounds__(128) void gcost_kernel(
    const float* __restrict__ x, const float* __restrict__ F2g,
    const float* __restrict__ alpha0, float* __restrict__ G)
{
    __shared__ __align__(16) float xs[GBN][GPAD];   // 33792 B
    __shared__ __align__(16) float fs[GBK][GPAD];   // 16896 B
    __shared__ float ps[GBK][4];                    // 512 B  (||F2||^2 partials)

    const int tid = threadIdx.x;
    const int n0  = blockIdx.x * GBN;
    const int k0  = blockIdx.y * GBK;

    // stage x tile: 64 rows x 32 float4, coalesced
    for (int i = tid; i < GBN * 32; i += 128) {
        int r = i >> 5, c = i & 31;
        int v = n0 + r; if (v >= NN) v = NN - 1;
        float4 w = reinterpret_cast<const float4*>(x + (size_t)v * NF)[c];
        *reinterpret_cast<float4*>(&xs[r][c * 4]) = w;
    }
    // stage F2 tile: 32 rows x 32 float4
    for (int i = tid; i < GBK * 32; i += 128) {
        int r = i >> 5, c = i & 31;
        float4 w = reinterpret_cast<const float4*>(F2g + (size_t)(k0 + r) * NF)[c];
        *reinterpret_cast<float4*>(&fs[r][c * 4]) = w;
    }
    __syncthreads();

    // ||F2||^2 partials
    {
        int r = tid & 31, q = tid >> 5;
        const float4* fp = reinterpret_cast<const float4*>(&fs[r][q * 32]);
        float s = 0.f;
        #pragma unroll
        for (int c = 0; c < 8; c++) {
            float4 w = fp[c];
            s += w.x * w.x + w.y * w.y + w.z * w.z + w.w * w.w;
        }
        ps[r][q] = s;
    }
    __syncthreads();

    const int jk = tid & 7;
    const int nn = tid >> 3;

    float acc[4][4];
    #pragma unroll
    for (int c = 0; c < 4; c++)
        #pragma unroll
        for (int t = 0; t < 4; t++) acc[c][t] = 0.f;

    #pragma unroll 4
    for (int f = 0; f < NF / 4; f++) {
        float4 xa[4], fb[4];
        #pragma unroll
        for (int c = 0; c < 4; c++)
            xa[c] = *reinterpret_cast<const float4*>(&xs[nn + 16 * c][f * 4]);
        #pragma unroll
        for (int t = 0; t < 4; t++)
            fb[t] = *reinterpret_cast<const float4*>(&fs[jk + 8 * t][f * 4]);
        #pragma unroll
        for (int c = 0; c < 4; c++)
            #pragma unroll
            for (int t = 0; t < 4; t++) {
                acc[c][t] = fmaf(xa[c].x, fb[t].x, acc[c][t]);
                acc[c][t] = fmaf(xa[c].y, fb[t].y, acc[c][t]);
                acc[c][t] = fmaf(xa[c].z, fb[t].z, acc[c][t]);
                acc[c][t] = fmaf(xa[c].w, fb[t].w, acc[c][t]);
            }
    }

    const float alpha  = 1.f / (1.f + __expf(-alpha0[0]));
    const float mcoefl = (1.f - alpha) * 10.f * LOG2E;
    const float m2     = -2.f * mcoefl;

    #pragma unroll
    for (int t = 0; t < 4; t++) {
        int krow = jk + 8 * t;
        float sq   = ps[krow][0] + ps[krow][1] + ps[krow][2] + ps[krow][3];
        float base = mcoefl * sq;
        int   kt   = k0 + krow;
        #pragma unroll
        for (int c = 0; c < 4; c++) {
            int v = n0 + nn + 16 * c;
            if (v < NN)
                G[(size_t)v * (NTPL * MT) + kt] = fmaf(m2, acc[c][t], base);
        }
    }
}

// ---------------- main kernel: r13 math, persistent tile loop
__global__ __launch_bounds__(BS, 4) void srfgw_kernel(
    const float* __restrict__ x,
    const int*   __restrict__ dst,
    const float* __restrict__ C2g,
    const float* __restrict__ F2g,
    const float* __restrict__ alpha0,
    const float* __restrict__ G,
    int useG,
    float*       __restrict__ out)
{
    const int tid = threadIdx.x;

    __shared__ __align__(16) float s_T[KPB][NPB][MM][RS];     // 22848 B
    __shared__ __align__(16) float s_C2sq[KPB][MT][RS];       // 1920 B
    __shared__ __align__(16) float s_q[KPB][NPB][RS];         // 1344 B
    __shared__ __align__(16) float s_cc[KPB][NPB][RS];        // 1344 B
    __shared__ __align__(16) float s_A[KPB][RS];              // 192 B
    __shared__ __align__(16) float s_B[KPB][RS];              // 192 B
    __shared__ __align__(16) int   s_adj[NPB * MM][DEG];      // 7616 B
    __shared__ int      s_nbr[NPB][MM];
    __shared__ unsigned s_mask[NPB][MM];

    const float aval  = alpha0[0];
    const float alpha = 1.f / (1.f + __expf(-aval));
    const float gcoef = 2.f * alpha * 10.f;
    const float tgl   = 2.f * gcoef * LOG2E;
    const float gl2   = gcoef * LOG2E;

    // ---- tile-invariant thread roles ----
    const int  kh     = tid >> 7;              // 0..3
    const int  L      = tid & 127;
    const bool rvalid = L < NPB * MM;          // 119
    int gR = L / MM;
    int aR = L - gR * MM;
    if (!rvalid) { gR = 0; aR = 0; }

    const bool cvalid = tid < KPB * NPB * MT;  // 280
    int ck = 0, cn = 0, ct = 0;
    if (cvalid) {
        ck = tid / (NPB * MT);
        int rem = tid - ck * (NPB * MT);
        cn = rem / MT;
        ct = rem - cn * MT;
    }

    float4* Trow = reinterpret_cast<float4*>(&s_T[kh][gR][aR][0]);

    for (int tile = blockIdx.x; tile < NTILES; tile += gridDim.x) {
        const int nb = (tile >> 2) * NPB;
        const int kb = (tile & 3) * KPB;

        // nbr (119 <= BS); node clamp: 7 does not divide 6000
        if (tid < NPB * MM) {
            int node = tid / MM, a0 = tid - node * MM;
            int nd  = nb + node;
            int ndc = nd < NN ? nd : NN - 1;
            s_nbr[node][a0]  = (a0 == 0) ? ndc : dst[(size_t)ndc * DEG + a0 - 1];
            s_mask[node][a0] = 0u;
        }
        __syncthreads();

        // adjacency rows (1904 > BS -> strided)
        for (int i = tid; i < NPB * MM * DEG; i += BS) {
            int r = i >> 4, j = i & 15;
            int node = r / MM, a0 = r - node * MM;
            s_adj[r][j] = dst[(size_t)s_nbr[node][a0] * DEG + j];
        }
        // C2sq (strided; kb offset)
        for (int i = tid; i < KPB * MT * MT; i += BS) {
            int kk = i / (MT * MT), rr = i - kk * (MT * MT);
            int rs = rr / MT, rt = rr - rs * MT;
            float v = C2g[(size_t)kb * MT * MT + i];
            s_C2sq[kk][rs][rt] = gl2 * v * v;
        }
        // iter-0 fold constants (40 <= BS)
        if (tid < KPB * MT) {
            int kk = tid / MT, s = tid - kk * MT;
            const float* cr = C2g + (size_t)(kb + kk) * MT * MT + s * MT;
            float rs = 0.f, rq = 0.f;
            #pragma unroll
            for (int t = 0; t < MT; t++) { float c = cr[t]; rs += c; rq = fmaf(c, c, rq); }
            s_A[kk][s] = (tgl / 170.f) * rs;
            s_B[kk][s] = 0.1f * gl2 * rq;
        }
        __syncthreads();

        // masks (2023 > BS -> strided), dual atomicOr symmetrization
        for (int i = tid; i < NPB * MM * MM; i += BS) {
            int node = i / (MM * MM), rr = i - node * (MM * MM);
            int pa = rr / MM, pb = rr - pa * MM;
            int vtgt = s_nbr[node][pb];
            const int* ar = s_adj[node * MM + pa];
            bool e = false;
            #pragma unroll
            for (int j = 0; j < DEG; j++) e = e | (ar[j] == vtgt);
            if (e) {
                atomicOr(&s_mask[node][pa], 1u << pb);
                atomicOr(&s_mask[node][pb], 1u << pa);
            }
        }
        __syncthreads();

        const int k_u = __builtin_amdgcn_readfirstlane(kb + kh);
        const float* __restrict__ c2p = C2g + (size_t)k_u * MT * MT;

        const int vv = s_nbr[gR][aR];

        float Mc[MT];
        if (useG) {
            const float2* gp = reinterpret_cast<const float2*>(G + (size_t)vv * (NTPL * MT) + k_u * MT);
            #pragma unroll
            for (int j = 0; j < 5; j++) {
                float2 w = gp[j];
                Mc[2 * j] = w.x; Mc[2 * j + 1] = w.y;
            }
        } else {
            float dot[MT], sq2[MT];
            #pragma unroll
            for (int t = 0; t < MT; t++) { dot[t] = 0.f; sq2[t] = 0.f; }
            const float4* xr = reinterpret_cast<const float4*>(x + (size_t)vv * NF);
            const float4* fr = reinterpret_cast<const float4*>(F2g + (size_t)k_u * MT * NF);
            for (int f = 0; f < NF / 4; f++) {
                float4 xa = xr[f];
                #pragma unroll
                for (int t = 0; t < MT; t++) {
                    float4 b = fr[t * (NF / 4) + f];
                    dot[t] += xa.x * b.x + xa.y * b.y + xa.z * b.z + xa.w * b.w;
                    sq2[t] += b.x * b.x + b.y * b.y + b.z * b.z + b.w * b.w;
                }
            }
            const float mcoefl = (1.f - alpha) * 10.f * LOG2E;
            #pragma unroll
            for (int t = 0; t < MT; t++) Mc[t] = mcoefl * (sq2[t] - 2.f * dot[t]);
        }

        unsigned mask = rvalid ? s_mask[gR][aR] : 0u;
        const int  pcnt = __popc(mask);
        const bool cmpl = pcnt > 8;
        unsigned   lmask = cmpl ? (~mask & 0x1FFFFu) : mask;
        if (!rvalid) lmask = 0u;
        const float sgn = cmpl ? -1.f : 1.f;
        const float P   = 1.f / 17.f;

        // ---- iter-0 analytic fold ----
        float lt[MT];
        {
            const float pcf = (float)pcnt;
            const float2* Ap = reinterpret_cast<const float2*>(&s_A[kh][0]);
            const float2* Bp = reinterpret_cast<const float2*>(&s_B[kh][0]);
            #pragma unroll
            for (int j = 0; j < 5; j++) {
                float2 av = Ap[j], bv = Bp[j];
                lt[2 * j]     = fmaf(pcf, av.x, -bv.x - Mc[2 * j]);
                lt[2 * j + 1] = fmaf(pcf, av.y, -bv.y - Mc[2 * j + 1]);
            }
        }

        float qa = 0.f;

        for (int it = 1; it <= NITER; it++) {
            // thread-local softmax (log2 domain)
            float mx = lt[0];
            #pragma unroll
            for (int t = 1; t < MT; t++) mx = fmaxf(mx, lt[t]);
            float e[MT], ss = 0.f;
            #pragma unroll
            for (int t = 0; t < MT; t++) { e[t] = fexp2(lt[t] - mx); ss += e[t]; }
            float sc = P * frcp(ss);
            #pragma unroll
            for (int t = 0; t < MT; t++) e[t] *= sc;

            if (rvalid) {
                Trow[0] = make_float4(e[0], e[1], e[2], e[3]);
                Trow[1] = make_float4(e[4], e[5], e[6], e[7]);
                reinterpret_cast<float2*>(Trow)[4] = make_float2(e[8], e[9]);
            }
            __syncthreads();                         // (1) T visible

            // colsum -> q
            if (cvalid) {
                const float* colp = &s_T[ck][cn][0][ct];
                float s0 = 0.f;
                #pragma unroll
                for (int m = 0; m < MM; m++) s0 += colp[m * RS];
                qa = s0;
                s_q[ck][cn][ct] = s0;
            }
            __syncthreads();                         // (2) q visible
            if (it == NITER) break;

            // cc (cvalid threads)
            if (cvalid) {
                const float4* qp4 = reinterpret_cast<const float4*>(&s_q[ck][cn][0]);
                float4 qx = qp4[0], qy = qp4[1];
                float2 qz = reinterpret_cast<const float2*>(qp4)[4];
                const float4* cr = reinterpret_cast<const float4*>(&s_C2sq[ck][ct][0]);
                float4 ca = cr[0], cb = cr[1];
                float2 c2 = reinterpret_cast<const float2*>(cr)[4];
                float cc = qx.x * ca.x + qx.y * ca.y + qx.z * ca.z + qx.w * ca.w
                         + qy.x * cb.x + qy.y * cb.y + qy.z * cb.z + qy.w * cb.w
                         + qz.x * c2.x + qz.y * c2.y;
                s_cc[ck][cn][ct] = cc;
            }

            // row work: q read, Y1, y2 matvec, partial update (pre-ccr)
            float q[MT];
            {
                const float4* qp4 = reinterpret_cast<const float4*>(&s_q[kh][gR][0]);
                float4 qx = qp4[0], qy = qp4[1];
                float2 qz = reinterpret_cast<const float2*>(qp4)[4];
                q[0] = qx.x; q[1] = qx.y; q[2] = qx.z; q[3] = qx.w;
                q[4] = qy.x; q[5] = qy.y; q[6] = qy.z; q[7] = qy.w;
                q[8] = qz.x; q[9] = qz.y;
            }
            float y1[MT];
            #pragma unroll
            for (int t = 0; t < MT; t++) y1[t] = cmpl ? q[t] : 0.f;
            unsigned mm = lmask;
            while (mm) {
                int b = __ffs(mm) - 1;
                mm &= mm - 1;
                const float4* rb4 = reinterpret_cast<const float4*>(&s_T[kh][gR][b][0]);
                float4 ra = rb4[0], rb = rb4[1];
                float2 rc = reinterpret_cast<const float2*>(rb4)[4];
                y1[0] += sgn * ra.x; y1[1] += sgn * ra.y; y1[2] += sgn * ra.z; y1[3] += sgn * ra.w;
                y1[4] += sgn * rb.x; y1[5] += sgn * rb.y; y1[6] += sgn * rb.z; y1[7] += sgn * rb.w;
                y1[8] += sgn * rc.x; y1[9] += sgn * rc.y;
            }
            #pragma unroll
            for (int s = 0; s < MT; s++) {
                float y2 = 0.f;
                #pragma unroll
                for (int t = 0; t < MT; t++) y2 = fmaf(y1[t], c2p[s * MT + t], y2);
                lt[s] += tgl * y2 - Mc[s];           // ccr applied after barrier
            }
            __syncthreads();                         // (3) cc visible

            {
                const float4* cp = reinterpret_cast<const float4*>(&s_cc[kh][gR][0]);
                float4 ca = cp[0], cb = cp[1];
                float2 c2 = reinterpret_cast<const float2*>(cp)[4];
                lt[0] -= ca.x; lt[1] -= ca.y; lt[2] -= ca.z; lt[3] -= ca.w;
                lt[4] -= cb.x; lt[5] -= cb.y; lt[6] -= cb.z; lt[7] -= cb.w;
                lt[8] -= c2.x; lt[9] -= c2.y;
            }
        }

        if (cvalid) {
            int nOut = nb + cn;
            if (nOut < NN)
                out[(size_t)nOut * (NTPL * MT) + (kb + ck) * MT + ct] = qa;
        }
        // tile seam: all LDS reads of setup structures completed before the
        // final barrier (2) above; safe to overwrite s_nbr/s_adj next tile.
    }
}

extern "C" void kernel_launch(void* const* d_in, const int* in_sizes, int n_in,
                              void* d_out, int out_size, void* d_ws, size_t ws_size,
                              hipStream_t stream) {
    const float* x      = (const float*)d_in[0];
    const int*   eidx   = (const int*)d_in[1];
    const float* tmpl   = (const float*)d_in[2];
    const float* tmplf  = (const float*)d_in[3];
    const float* alpha0 = (const float*)d_in[4];
    float*       outp   = (float*)d_out;

    const int* dst = eidx + NN * DEG;
    float* G = (float*)d_ws;
    const size_t gbytes = (size_t)NN * NTPL * MT * sizeof(float);
    int useG = (ws_size >= gbytes) ? 1 : 0;

    if (useG)
        gcost_kernel<<<dim3((NN + GBN - 1) / GBN, NTPL * MT / GBK), dim3(128), 0, stream>>>(
            x, tmplf, alpha0, G);

    srfgw_kernel<<<dim3(PGRID), dim3(BS), 0, stream>>>(
        x, dst, tmpl, tmplf, alpha0, G, useG, outp);
}

// Round 3
// 208.383 us; speedup vs baseline: 1.0872x; 1.0872x over previous
//
#include <hip/hip_runtime.h>

// LTFGW semi-relaxed FGW — round 17: revert persistent grid + 2 issue-count cuts.
// r16 post-mortem: persistent 1024-block grid REGRESSED 142->167.6 us
//   (VGPR 36->48 from loop-carried state; tile t+1 setup serialized behind
//   tile t instead of overlapping as independent blocks; occupancy 60->38).
//   HW backfill dispatch beats an explicit tile loop here. Reverted.
// r17 (on r13 base, launch dim3(858,4)):
//   (a) y2 matvec uses C2 symmetry (templates are exactly 0.5(T+T^T) in fp32)
//       -> s-contiguous reads -> float2 ext_vector packed FMA: 100 -> ~50
//       VALU slots for the biggest per-iter block.
//   (b) colsum column-pairing: 140 threads x 17 ds_read_b64 instead of
//       280 x 17 ds_read_b32; q write + final out become 8B ops.
//   Pipes model: VALU ~65us, LDS ~75-100us, wall 142 ~ sum (barriers
//   phase-serialize) -> count cuts convert ~1:1 to wall.
// srfgw otherwise byte-identical to r13; gcost v6 verbatim.

#define NN    6000
#define DEG   16
#define MM    17
#define NTPL  16
#define MT    10
#define NF    128
#define NITER 10
#define KPB   4
#define NPB   7
#define BS    512
#define RS    12            // padded T row stride (floats)
#define LOG2E 1.44269504088896340736f

typedef float v2f __attribute__((ext_vector_type(2)));

__device__ __forceinline__ float fexp2(float x) { return __builtin_amdgcn_exp2f(x); }
__device__ __forceinline__ float frcp(float x)  { return __builtin_amdgcn_rcpf(x); }

// ---------------- gcost v6: tiled SGEMM G[v,kt] = mcoefl*(||F2[kt]||^2 - 2 x[v].F2[kt])
#define GBN  64             // nodes per block
#define GBK  32             // kts per block
#define GPAD 132            // LDS row stride in floats

__global__ __launch_bounds__(128) void gcost_kernel(
    const float* __restrict__ x, const float* __restrict__ F2g,
    const float* __restrict__ alpha0, float* __restrict__ G)
{
    __shared__ __align__(16) float xs[GBN][GPAD];   // 33792 B
    __shared__ __align__(16) float fs[GBK][GPAD];   // 16896 B
    __shared__ float ps[GBK][4];                    // 512 B

    const int tid = threadIdx.x;
    const int n0  = blockIdx.x * GBN;
    const int k0  = blockIdx.y * GBK;

    for (int i = tid; i < GBN * 32; i += 128) {
        int r = i >> 5, c = i & 31;
        int v = n0 + r; if (v >= NN) v = NN - 1;
        float4 w = reinterpret_cast<const float4*>(x + (size_t)v * NF)[c];
        *reinterpret_cast<float4*>(&xs[r][c * 4]) = w;
    }
    for (int i = tid; i < GBK * 32; i += 128) {
        int r = i >> 5, c = i & 31;
        float4 w = reinterpret_cast<const float4*>(F2g + (size_t)(k0 + r) * NF)[c];
        *reinterpret_cast<float4*>(&fs[r][c * 4]) = w;
    }
    __syncthreads();

    {
        int r = tid & 31, q = tid >> 5;
        const float4* fp = reinterpret_cast<const float4*>(&fs[r][q * 32]);
        float s = 0.f;
        #pragma unroll
        for (int c = 0; c < 8; c++) {
            float4 w = fp[c];
            s += w.x * w.x + w.y * w.y + w.z * w.z + w.w * w.w;
        }
        ps[r][q] = s;
    }
    __syncthreads();

    const int jk = tid & 7;
    const int nn = tid >> 3;

    float acc[4][4];
    #pragma unroll
    for (int c = 0; c < 4; c++)
        #pragma unroll
        for (int t = 0; t < 4; t++) acc[c][t] = 0.f;

    #pragma unroll 4
    for (int f = 0; f < NF / 4; f++) {
        float4 xa[4], fb[4];
        #pragma unroll
        for (int c = 0; c < 4; c++)
            xa[c] = *reinterpret_cast<const float4*>(&xs[nn + 16 * c][f * 4]);
        #pragma unroll
        for (int t = 0; t < 4; t++)
            fb[t] = *reinterpret_cast<const float4*>(&fs[jk + 8 * t][f * 4]);
        #pragma unroll
        for (int c = 0; c < 4; c++)
            #pragma unroll
            for (int t = 0; t < 4; t++) {
                acc[c][t] = fmaf(xa[c].x, fb[t].x, acc[c][t]);
                acc[c][t] = fmaf(xa[c].y, fb[t].y, acc[c][t]);
                acc[c][t] = fmaf(xa[c].z, fb[t].z, acc[c][t]);
                acc[c][t] = fmaf(xa[c].w, fb[t].w, acc[c][t]);
            }
    }

    const float alpha  = 1.f / (1.f + __expf(-alpha0[0]));
    const float mcoefl = (1.f - alpha) * 10.f * LOG2E;
    const float m2     = -2.f * mcoefl;

    #pragma unroll
    for (int t = 0; t < 4; t++) {
        int krow = jk + 8 * t;
        float sq   = ps[krow][0] + ps[krow][1] + ps[krow][2] + ps[krow][3];
        float base = mcoefl * sq;
        int   kt   = k0 + krow;
        #pragma unroll
        for (int c = 0; c < 4; c++) {
            int v = n0 + nn + 16 * c;
            if (v < NN)
                G[(size_t)v * (NTPL * MT) + kt] = fmaf(m2, acc[c][t], base);
        }
    }
}

// ---------------- main kernel (r13 base + packed y2 + paired colsum)
__global__ __launch_bounds__(BS, 4) void srfgw_kernel(
    const float* __restrict__ x,
    const int*   __restrict__ dst,
    const float* __restrict__ C2g,
    const float* __restrict__ F2g,
    const float* __restrict__ alpha0,
    const float* __restrict__ G,
    int useG,
    float*       __restrict__ out)
{
    const int nb  = blockIdx.x * NPB;
    const int kb  = blockIdx.y * KPB;
    const int tid = threadIdx.x;

    __shared__ __align__(16) float s_T[KPB][NPB][MM][RS];     // 22848 B
    __shared__ __align__(16) float s_C2sq[KPB][MT][RS];       // 1920 B
    __shared__ __align__(16) float s_q[KPB][NPB][RS];         // 1344 B
    __shared__ __align__(16) float s_cc[KPB][NPB][RS];        // 1344 B
    __shared__ __align__(16) float s_A[KPB][RS];              // 192 B
    __shared__ __align__(16) float s_B[KPB][RS];              // 192 B
    __shared__ __align__(16) int   s_adj[NPB * MM][DEG];      // 7616 B
    __shared__ int      s_nbr[NPB][MM];
    __shared__ unsigned s_mask[NPB][MM];

    const float aval  = alpha0[0];
    const float alpha = 1.f / (1.f + __expf(-aval));
    const float gcoef = 2.f * alpha * 10.f;
    const float tgl   = 2.f * gcoef * LOG2E;
    const float gl2   = gcoef * LOG2E;

    // nbr (119 <= BS); node clamp: 7 does not divide 6000
    if (tid < NPB * MM) {
        int node = tid / MM, a0 = tid - node * MM;
        int nd  = nb + node;
        int ndc = nd < NN ? nd : NN - 1;
        s_nbr[node][a0]  = (a0 == 0) ? ndc : dst[(size_t)ndc * DEG + a0 - 1];
        s_mask[node][a0] = 0u;
    }
    __syncthreads();

    // adjacency rows (1904 > BS -> strided)
    for (int i = tid; i < NPB * MM * DEG; i += BS) {
        int r = i >> 4, j = i & 15;
        int node = r / MM, a0 = r - node * MM;
        s_adj[r][j] = dst[(size_t)s_nbr[node][a0] * DEG + j];
    }
    // C2sq (strided; kb offset)
    for (int i = tid; i < KPB * MT * MT; i += BS) {
        int kk = i / (MT * MT), rr = i - kk * (MT * MT);
        int rs = rr / MT, rt = rr - rs * MT;
        float v = C2g[(size_t)kb * MT * MT + i];
        s_C2sq[kk][rs][rt] = gl2 * v * v;
    }
    // iter-0 fold constants (40 <= BS)
    if (tid < KPB * MT) {
        int kk = tid / MT, s = tid - kk * MT;
        const float* cr = C2g + (size_t)(kb + kk) * MT * MT + s * MT;
        float rs = 0.f, rq = 0.f;
        #pragma unroll
        for (int t = 0; t < MT; t++) { float c = cr[t]; rs += c; rq = fmaf(c, c, rq); }
        s_A[kk][s] = (tgl / 170.f) * rs;
        s_B[kk][s] = 0.1f * gl2 * rq;
    }
    __syncthreads();

    // masks (2023 > BS -> strided), dual atomicOr symmetrization
    for (int i = tid; i < NPB * MM * MM; i += BS) {
        int node = i / (MM * MM), rr = i - node * (MM * MM);
        int pa = rr / MM, pb = rr - pa * MM;
        int vtgt = s_nbr[node][pb];
        const int* ar = s_adj[node * MM + pa];
        bool e = false;
        #pragma unroll
        for (int j = 0; j < DEG; j++) e = e | (ar[j] == vtgt);
        if (e) {
            atomicOr(&s_mask[node][pa], 1u << pb);
            atomicOr(&s_mask[node][pb], 1u << pa);
        }
    }
    __syncthreads();

    // ---- row mapping: kh wave-uniform; 119 rows flat-packed in 128 lanes ----
    const int  kh     = tid >> 7;              // 0..3
    const int  L      = tid & 127;
    const bool rvalid = L < NPB * MM;          // 119
    int gR = L / MM;
    int aR = L - gR * MM;
    if (!rvalid) { gR = 0; aR = 0; }

    const int k_u = __builtin_amdgcn_readfirstlane(kb + kh);
    const float* __restrict__ c2p = C2g + (size_t)k_u * MT * MT;

    const int vv = s_nbr[gR][aR];

    float Mc[MT];
    if (useG) {
        const float2* gp = reinterpret_cast<const float2*>(G + (size_t)vv * (NTPL * MT) + k_u * MT);
        #pragma unroll
        for (int j = 0; j < 5; j++) {
            float2 w = gp[j];
            Mc[2 * j] = w.x; Mc[2 * j + 1] = w.y;
        }
    } else {
        float dot[MT], sq2[MT];
        #pragma unroll
        for (int t = 0; t < MT; t++) { dot[t] = 0.f; sq2[t] = 0.f; }
        const float4* xr = reinterpret_cast<const float4*>(x + (size_t)vv * NF);
        const float4* fr = reinterpret_cast<const float4*>(F2g + (size_t)k_u * MT * NF);
        for (int f = 0; f < NF / 4; f++) {
            float4 xa = xr[f];
            #pragma unroll
            for (int t = 0; t < MT; t++) {
                float4 b = fr[t * (NF / 4) + f];
                dot[t] += xa.x * b.x + xa.y * b.y + xa.z * b.z + xa.w * b.w;
                sq2[t] += b.x * b.x + b.y * b.y + b.z * b.z + b.w * b.w;
            }
        }
        const float mcoefl = (1.f - alpha) * 10.f * LOG2E;
        #pragma unroll
        for (int t = 0; t < MT; t++) Mc[t] = mcoefl * (sq2[t] - 2.f * dot[t]);
    }

    unsigned mask = rvalid ? s_mask[gR][aR] : 0u;
    const int  pcnt = __popc(mask);
    const bool cmpl = pcnt > 8;
    unsigned   lmask = cmpl ? (~mask & 0x1FFFFu) : mask;
    if (!rvalid) lmask = 0u;
    const float sgn = cmpl ? -1.f : 1.f;
    const float P   = 1.f / 17.f;

    // ---- iter-0 analytic fold ----
    float lt[MT];
    {
        const float pcf = (float)pcnt;
        const float2* Ap = reinterpret_cast<const float2*>(&s_A[kh][0]);
        const float2* Bp = reinterpret_cast<const float2*>(&s_B[kh][0]);
        #pragma unroll
        for (int j = 0; j < 5; j++) {
            float2 av = Ap[j], bv = Bp[j];
            lt[2 * j]     = fmaf(pcf, av.x, -bv.x - Mc[2 * j]);
            lt[2 * j + 1] = fmaf(pcf, av.y, -bv.y - Mc[2 * j + 1]);
        }
    }

    // ---- colsum mapping (paired cols): tid < 140 -> (sk, sn, sp) ----
    const bool csum_valid = tid < KPB * NPB * 5;   // 140
    int sk = 0, sn = 0, sp = 0;
    if (csum_valid) {
        sk = tid / (NPB * 5);
        int rem = tid - sk * (NPB * 5);
        sn = rem / 5;
        sp = rem - sn * 5;
    }
    v2f qa2 = {0.f, 0.f};

    // ---- cc mapping: tid < 280 -> (ck, cn, ct) ----
    const bool cvalid = tid < KPB * NPB * MT;  // 280
    int ck = 0, cn = 0, ct = 0;
    if (cvalid) {
        ck = tid / (NPB * MT);
        int rem = tid - ck * (NPB * MT);
        cn = rem / MT;
        ct = rem - cn * MT;
    }

    float4* Trow = reinterpret_cast<float4*>(&s_T[kh][gR][aR][0]);

    for (int it = 1; it <= NITER; it++) {
        // thread-local softmax (log2 domain)
        float mx = lt[0];
        #pragma unroll
        for (int t = 1; t < MT; t++) mx = fmaxf(mx, lt[t]);
        float e[MT], ss = 0.f;
        #pragma unroll
        for (int t = 0; t < MT; t++) { e[t] = fexp2(lt[t] - mx); ss += e[t]; }
        float sc = P * frcp(ss);
        #pragma unroll
        for (int t = 0; t < MT; t++) e[t] *= sc;

        if (rvalid) {
            Trow[0] = make_float4(e[0], e[1], e[2], e[3]);
            Trow[1] = make_float4(e[4], e[5], e[6], e[7]);
            reinterpret_cast<float2*>(Trow)[4] = make_float2(e[8], e[9]);
        }
        __syncthreads();                         // (1) T visible

        // colsum -> q (column pairs, b64 reads)
        if (csum_valid) {
            const float* colp = &s_T[sk][sn][0][2 * sp];
            v2f s0 = {0.f, 0.f};
            #pragma unroll
            for (int m = 0; m < MM; m++) {
                v2f v = *reinterpret_cast<const v2f*>(&colp[m * RS]);
                s0 += v;
            }
            qa2 = s0;
            *reinterpret_cast<v2f*>(&s_q[sk][sn][2 * sp]) = s0;
        }
        __syncthreads();                         // (2) q visible
        if (it == NITER) break;

        // cc (cvalid threads)
        if (cvalid) {
            const float4* qp4 = reinterpret_cast<const float4*>(&s_q[ck][cn][0]);
            float4 qx = qp4[0], qy = qp4[1];
            float2 qz = reinterpret_cast<const float2*>(qp4)[4];
            const float4* cr = reinterpret_cast<const float4*>(&s_C2sq[ck][ct][0]);
            float4 ca = cr[0], cb = cr[1];
            float2 c2 = reinterpret_cast<const float2*>(cr)[4];
            float cc = qx.x * ca.x + qx.y * ca.y + qx.z * ca.z + qx.w * ca.w
                     + qy.x * cb.x + qy.y * cb.y + qy.z * cb.z + qy.w * cb.w
                     + qz.x * c2.x + qz.y * c2.y;
            s_cc[ck][cn][ct] = cc;
        }

        // row work: q read, Y1, y2 matvec, partial update (pre-ccr)
        float q[MT];
        {
            const float4* qp4 = reinterpret_cast<const float4*>(&s_q[kh][gR][0]);
            float4 qx = qp4[0], qy = qp4[1];
            float2 qz = reinterpret_cast<const float2*>(qp4)[4];
            q[0] = qx.x; q[1] = qx.y; q[2] = qx.z; q[3] = qx.w;
            q[4] = qy.x; q[5] = qy.y; q[6] = qy.z; q[7] = qy.w;
            q[8] = qz.x; q[9] = qz.y;
        }
        float y1[MT];
        #pragma unroll
        for (int t = 0; t < MT; t++) y1[t] = cmpl ? q[t] : 0.f;
        unsigned mm = lmask;
        while (mm) {
            int b = __ffs(mm) - 1;
            mm &= mm - 1;
            const float4* rb4 = reinterpret_cast<const float4*>(&s_T[kh][gR][b][0]);
            float4 ra = rb4[0], rb = rb4[1];
            float2 rc = reinterpret_cast<const float2*>(rb4)[4];
            y1[0] += sgn * ra.x; y1[1] += sgn * ra.y; y1[2] += sgn * ra.z; y1[3] += sgn * ra.w;
            y1[4] += sgn * rb.x; y1[5] += sgn * rb.y; y1[6] += sgn * rb.z; y1[7] += sgn * rb.w;
            y1[8] += sgn * rc.x; y1[9] += sgn * rc.y;
        }

        // y2 matvec, packed over s (C2 symmetric: y2[s] = sum_t y1[t]*C2[t][s],
        // s-contiguous reads -> v_pk_fma_f32)
        {
            v2f y2v[5];
            #pragma unroll
            for (int sv = 0; sv < 5; sv++) y2v[sv] = (v2f){0.f, 0.f};
            #pragma unroll
            for (int t = 0; t < MT; t++) {
                const float y1t = y1[t];
                const v2f yt2 = {y1t, y1t};
                const float* crow = c2p + t * MT;
                #pragma unroll
                for (int sv = 0; sv < 5; sv++) {
                    v2f c = *reinterpret_cast<const v2f*>(crow + 2 * sv);
                    y2v[sv] += yt2 * c;
                }
            }
            #pragma unroll
            for (int sv = 0; sv < 5; sv++) {
                lt[2 * sv]     += tgl * y2v[sv].x - Mc[2 * sv];
                lt[2 * sv + 1] += tgl * y2v[sv].y - Mc[2 * sv + 1];
            }
        }
        __syncthreads();                         // (3) cc visible

        {
            const float4* cp = reinterpret_cast<const float4*>(&s_cc[kh][gR][0]);
            float4 ca = cp[0], cb = cp[1];
            float2 c2 = reinterpret_cast<const float2*>(cp)[4];
            lt[0] -= ca.x; lt[1] -= ca.y; lt[2] -= ca.z; lt[3] -= ca.w;
            lt[4] -= cb.x; lt[5] -= cb.y; lt[6] -= cb.z; lt[7] -= cb.w;
            lt[8] -= c2.x; lt[9] -= c2.y;
        }
    }

    if (csum_valid) {
        int nOut = nb + sn;
        if (nOut < NN) {
            float* op = out + (size_t)nOut * (NTPL * MT) + (kb + sk) * MT + 2 * sp;
            *reinterpret_cast<v2f*>(op) = qa2;
        }
    }
}

extern "C" void kernel_launch(void* const* d_in, const int* in_sizes, int n_in,
                              void* d_out, int out_size, void* d_ws, size_t ws_size,
                              hipStream_t stream) {
    const float* x      = (const float*)d_in[0];
    const int*   eidx   = (const int*)d_in[1];
    const float* tmpl   = (const float*)d_in[2];
    const float* tmplf  = (const float*)d_in[3];
    const float* alpha0 = (const float*)d_in[4];
    float*       outp   = (float*)d_out;

    const int* dst = eidx + NN * DEG;
    float* G = (float*)d_ws;
    const size_t gbytes = (size_t)NN * NTPL * MT * sizeof(float);
    int useG = (ws_size >= gbytes) ? 1 : 0;

    if (useG)
        gcost_kernel<<<dim3((NN + GBN - 1) / GBN, NTPL * MT / GBK), dim3(128), 0, stream>>>(
            x, tmplf, alpha0, G);

    srfgw_kernel<<<dim3((NN + NPB - 1) / NPB, NTPL / KPB), dim3(BS), 0, stream>>>(
        x, dst, tmpl, tmplf, alpha0, G, useG, outp);
}

// Round 4
// 206.628 us; speedup vs baseline: 1.0964x; 1.0085x over previous
//
#include <hip/hip_runtime.h>

// LTFGW semi-relaxed FGW — round 18: r13 revert + SMEM-safe packed y2 (isolated).
// r17 post-mortem (+5.4us): v2f loads from uniform c2p defeated SMEM promotion
//   -> per-lane VMEM loads in the hot loop instead of SGPR-resident constants.
//   Colsum b64 pairing also mildly negative (conflicts 6.83M->6.96M). Reverted.
// r18: y2 matvec only change vs r13. C2 symmetric -> y2[s]=sum_t y1[t]*C2[t][s]
//   with s-contiguous reads; v2f accumulators; operand pair built from TWO
//   SCALAR loads (uniform -> adjacent SGPRs via s_load_dwordx2) so v_pk_fma_f32
//   can take the SGPR-pair source + broadcast y1t. Worst case: compiler splits
//   back into 2x v_fmac = exactly r13 codegen (null, not regression).
// gcost: v6 verbatim (LDS-staged 64x32 SGEMM, ~6 us).

#define NN    6000
#define DEG   16
#define MM    17
#define NTPL  16
#define MT    10
#define NF    128
#define NITER 10
#define KPB   4
#define NPB   7
#define BS    512
#define RS    12            // padded T row stride (floats)
#define LOG2E 1.44269504088896340736f

typedef float v2f __attribute__((ext_vector_type(2)));

__device__ __forceinline__ float fexp2(float x) { return __builtin_amdgcn_exp2f(x); }
__device__ __forceinline__ float frcp(float x)  { return __builtin_amdgcn_rcpf(x); }

// ---------------- gcost v6: tiled SGEMM G[v,kt] = mcoefl*(||F2[kt]||^2 - 2 x[v].F2[kt])
#define GBN  64             // nodes per block
#define GBK  32             // kts per block
#define GPAD 132            // LDS row stride in floats

__global__ __launch_bounds__(128) void gcost_kernel(
    const float* __restrict__ x, const float* __restrict__ F2g,
    const float* __restrict__ alpha0, float* __restrict__ G)
{
    __shared__ __align__(16) float xs[GBN][GPAD];   // 33792 B
    __shared__ __align__(16) float fs[GBK][GPAD];   // 16896 B
    __shared__ float ps[GBK][4];                    // 512 B

    const int tid = threadIdx.x;
    const int n0  = blockIdx.x * GBN;
    const int k0  = blockIdx.y * GBK;

    for (int i = tid; i < GBN * 32; i += 128) {
        int r = i >> 5, c = i & 31;
        int v = n0 + r; if (v >= NN) v = NN - 1;
        float4 w = reinterpret_cast<const float4*>(x + (size_t)v * NF)[c];
        *reinterpret_cast<float4*>(&xs[r][c * 4]) = w;
    }
    for (int i = tid; i < GBK * 32; i += 128) {
        int r = i >> 5, c = i & 31;
        float4 w = reinterpret_cast<const float4*>(F2g + (size_t)(k0 + r) * NF)[c];
        *reinterpret_cast<float4*>(&fs[r][c * 4]) = w;
    }
    __syncthreads();

    {
        int r = tid & 31, q = tid >> 5;
        const float4* fp = reinterpret_cast<const float4*>(&fs[r][q * 32]);
        float s = 0.f;
        #pragma unroll
        for (int c = 0; c < 8; c++) {
            float4 w = fp[c];
            s += w.x * w.x + w.y * w.y + w.z * w.z + w.w * w.w;
        }
        ps[r][q] = s;
    }
    __syncthreads();

    const int jk = tid & 7;
    const int nn = tid >> 3;

    float acc[4][4];
    #pragma unroll
    for (int c = 0; c < 4; c++)
        #pragma unroll
        for (int t = 0; t < 4; t++) acc[c][t] = 0.f;

    #pragma unroll 4
    for (int f = 0; f < NF / 4; f++) {
        float4 xa[4], fb[4];
        #pragma unroll
        for (int c = 0; c < 4; c++)
            xa[c] = *reinterpret_cast<const float4*>(&xs[nn + 16 * c][f * 4]);
        #pragma unroll
        for (int t = 0; t < 4; t++)
            fb[t] = *reinterpret_cast<const float4*>(&fs[jk + 8 * t][f * 4]);
        #pragma unroll
        for (int c = 0; c < 4; c++)
            #pragma unroll
            for (int t = 0; t < 4; t++) {
                acc[c][t] = fmaf(xa[c].x, fb[t].x, acc[c][t]);
                acc[c][t] = fmaf(xa[c].y, fb[t].y, acc[c][t]);
                acc[c][t] = fmaf(xa[c].z, fb[t].z, acc[c][t]);
                acc[c][t] = fmaf(xa[c].w, fb[t].w, acc[c][t]);
            }
    }

    const float alpha  = 1.f / (1.f + __expf(-alpha0[0]));
    const float mcoefl = (1.f - alpha) * 10.f * LOG2E;
    const float m2     = -2.f * mcoefl;

    #pragma unroll
    for (int t = 0; t < 4; t++) {
        int krow = jk + 8 * t;
        float sq   = ps[krow][0] + ps[krow][1] + ps[krow][2] + ps[krow][3];
        float base = mcoefl * sq;
        int   kt   = k0 + krow;
        #pragma unroll
        for (int c = 0; c < 4; c++) {
            int v = n0 + nn + 16 * c;
            if (v < NN)
                G[(size_t)v * (NTPL * MT) + kt] = fmaf(m2, acc[c][t], base);
        }
    }
}

// ---------------- main kernel (r13 base; only y2 matvec changed)
__global__ __launch_bounds__(BS, 4) void srfgw_kernel(
    const float* __restrict__ x,
    const int*   __restrict__ dst,
    const float* __restrict__ C2g,
    const float* __restrict__ F2g,
    const float* __restrict__ alpha0,
    const float* __restrict__ G,
    int useG,
    float*       __restrict__ out)
{
    const int nb  = blockIdx.x * NPB;
    const int kb  = blockIdx.y * KPB;
    const int tid = threadIdx.x;

    __shared__ __align__(16) float s_T[KPB][NPB][MM][RS];     // 22848 B
    __shared__ __align__(16) float s_C2sq[KPB][MT][RS];       // 1920 B
    __shared__ __align__(16) float s_q[KPB][NPB][RS];         // 1344 B
    __shared__ __align__(16) float s_cc[KPB][NPB][RS];        // 1344 B
    __shared__ __align__(16) float s_A[KPB][RS];              // 192 B
    __shared__ __align__(16) float s_B[KPB][RS];              // 192 B
    __shared__ __align__(16) int   s_adj[NPB * MM][DEG];      // 7616 B
    __shared__ int      s_nbr[NPB][MM];
    __shared__ unsigned s_mask[NPB][MM];

    const float aval  = alpha0[0];
    const float alpha = 1.f / (1.f + __expf(-aval));
    const float gcoef = 2.f * alpha * 10.f;
    const float tgl   = 2.f * gcoef * LOG2E;
    const float gl2   = gcoef * LOG2E;

    // nbr (119 <= BS); node clamp: 7 does not divide 6000
    if (tid < NPB * MM) {
        int node = tid / MM, a0 = tid - node * MM;
        int nd  = nb + node;
        int ndc = nd < NN ? nd : NN - 1;
        s_nbr[node][a0]  = (a0 == 0) ? ndc : dst[(size_t)ndc * DEG + a0 - 1];
        s_mask[node][a0] = 0u;
    }
    __syncthreads();

    // adjacency rows (1904 > BS -> strided)
    for (int i = tid; i < NPB * MM * DEG; i += BS) {
        int r = i >> 4, j = i & 15;
        int node = r / MM, a0 = r - node * MM;
        s_adj[r][j] = dst[(size_t)s_nbr[node][a0] * DEG + j];
    }
    // C2sq (strided; kb offset)
    for (int i = tid; i < KPB * MT * MT; i += BS) {
        int kk = i / (MT * MT), rr = i - kk * (MT * MT);
        int rs = rr / MT, rt = rr - rs * MT;
        float v = C2g[(size_t)kb * MT * MT + i];
        s_C2sq[kk][rs][rt] = gl2 * v * v;
    }
    // iter-0 fold constants (40 <= BS)
    if (tid < KPB * MT) {
        int kk = tid / MT, s = tid - kk * MT;
        const float* cr = C2g + (size_t)(kb + kk) * MT * MT + s * MT;
        float rs = 0.f, rq = 0.f;
        #pragma unroll
        for (int t = 0; t < MT; t++) { float c = cr[t]; rs += c; rq = fmaf(c, c, rq); }
        s_A[kk][s] = (tgl / 170.f) * rs;
        s_B[kk][s] = 0.1f * gl2 * rq;
    }
    __syncthreads();

    // masks (2023 > BS -> strided), dual atomicOr symmetrization
    for (int i = tid; i < NPB * MM * MM; i += BS) {
        int node = i / (MM * MM), rr = i - node * (MM * MM);
        int pa = rr / MM, pb = rr - pa * MM;
        int vtgt = s_nbr[node][pb];
        const int* ar = s_adj[node * MM + pa];
        bool e = false;
        #pragma unroll
        for (int j = 0; j < DEG; j++) e = e | (ar[j] == vtgt);
        if (e) {
            atomicOr(&s_mask[node][pa], 1u << pb);
            atomicOr(&s_mask[node][pb], 1u << pa);
        }
    }
    __syncthreads();

    // ---- row mapping: kh wave-uniform; 119 rows flat-packed in 128 lanes ----
    const int  kh     = tid >> 7;              // 0..3
    const int  L      = tid & 127;
    const bool rvalid = L < NPB * MM;          // 119
    int gR = L / MM;
    int aR = L - gR * MM;
    if (!rvalid) { gR = 0; aR = 0; }

    const int k_u = __builtin_amdgcn_readfirstlane(kb + kh);
    const float* __restrict__ c2p = C2g + (size_t)k_u * MT * MT;

    const int vv = s_nbr[gR][aR];

    float Mc[MT];
    if (useG) {
        const float2* gp = reinterpret_cast<const float2*>(G + (size_t)vv * (NTPL * MT) + k_u * MT);
        #pragma unroll
        for (int j = 0; j < 5; j++) {
            float2 w = gp[j];
            Mc[2 * j] = w.x; Mc[2 * j + 1] = w.y;
        }
    } else {
        float dot[MT], sq2[MT];
        #pragma unroll
        for (int t = 0; t < MT; t++) { dot[t] = 0.f; sq2[t] = 0.f; }
        const float4* xr = reinterpret_cast<const float4*>(x + (size_t)vv * NF);
        const float4* fr = reinterpret_cast<const float4*>(F2g + (size_t)k_u * MT * NF);
        for (int f = 0; f < NF / 4; f++) {
            float4 xa = xr[f];
            #pragma unroll
            for (int t = 0; t < MT; t++) {
                float4 b = fr[t * (NF / 4) + f];
                dot[t] += xa.x * b.x + xa.y * b.y + xa.z * b.z + xa.w * b.w;
                sq2[t] += b.x * b.x + b.y * b.y + b.z * b.z + b.w * b.w;
            }
        }
        const float mcoefl = (1.f - alpha) * 10.f * LOG2E;
        #pragma unroll
        for (int t = 0; t < MT; t++) Mc[t] = mcoefl * (sq2[t] - 2.f * dot[t]);
    }

    unsigned mask = rvalid ? s_mask[gR][aR] : 0u;
    const int  pcnt = __popc(mask);
    const bool cmpl = pcnt > 8;
    unsigned   lmask = cmpl ? (~mask & 0x1FFFFu) : mask;
    if (!rvalid) lmask = 0u;
    const float sgn = cmpl ? -1.f : 1.f;
    const float P   = 1.f / 17.f;

    // ---- iter-0 analytic fold ----
    float lt[MT];
    {
        const float pcf = (float)pcnt;
        const float2* Ap = reinterpret_cast<const float2*>(&s_A[kh][0]);
        const float2* Bp = reinterpret_cast<const float2*>(&s_B[kh][0]);
        #pragma unroll
        for (int j = 0; j < 5; j++) {
            float2 av = Ap[j], bv = Bp[j];
            lt[2 * j]     = fmaf(pcf, av.x, -bv.x - Mc[2 * j]);
            lt[2 * j + 1] = fmaf(pcf, av.y, -bv.y - Mc[2 * j + 1]);
        }
    }

    // ---- colsum/cc mapping: tid < 280 -> (ck, cn, ct) ----
    const bool cvalid = tid < KPB * NPB * MT;  // 280
    int ck = 0, cn = 0, ct = 0;
    if (cvalid) {
        ck = tid / (NPB * MT);
        int rem = tid - ck * (NPB * MT);
        cn = rem / MT;
        ct = rem - cn * MT;
    }
    float qa = 0.f;

    float4* Trow = reinterpret_cast<float4*>(&s_T[kh][gR][aR][0]);

    for (int it = 1; it <= NITER; it++) {
        // thread-local softmax (log2 domain)
        float mx = lt[0];
        #pragma unroll
        for (int t = 1; t < MT; t++) mx = fmaxf(mx, lt[t]);
        float e[MT], ss = 0.f;
        #pragma unroll
        for (int t = 0; t < MT; t++) { e[t] = fexp2(lt[t] - mx); ss += e[t]; }
        float sc = P * frcp(ss);
        #pragma unroll
        for (int t = 0; t < MT; t++) e[t] *= sc;

        if (rvalid) {
            Trow[0] = make_float4(e[0], e[1], e[2], e[3]);
            Trow[1] = make_float4(e[4], e[5], e[6], e[7]);
            reinterpret_cast<float2*>(Trow)[4] = make_float2(e[8], e[9]);
        }
        __syncthreads();                         // (1) T visible

        // colsum -> q
        if (cvalid) {
            const float* colp = &s_T[ck][cn][0][ct];
            float s0 = 0.f;
            #pragma unroll
            for (int m = 0; m < MM; m++) s0 += colp[m * RS];
            qa = s0;
            s_q[ck][cn][ct] = s0;
        }
        __syncthreads();                         // (2) q visible
        if (it == NITER) break;

        // cc (cvalid threads)
        if (cvalid) {
            const float4* qp4 = reinterpret_cast<const float4*>(&s_q[ck][cn][0]);
            float4 qx = qp4[0], qy = qp4[1];
            float2 qz = reinterpret_cast<const float2*>(qp4)[4];
            const float4* cr = reinterpret_cast<const float4*>(&s_C2sq[ck][ct][0]);
            float4 ca = cr[0], cb = cr[1];
            float2 c2 = reinterpret_cast<const float2*>(cr)[4];
            float cc = qx.x * ca.x + qx.y * ca.y + qx.z * ca.z + qx.w * ca.w
                     + qy.x * cb.x + qy.y * cb.y + qy.z * cb.z + qy.w * cb.w
                     + qz.x * c2.x + qz.y * c2.y;
            s_cc[ck][cn][ct] = cc;
        }

        // row work: q read, Y1, y2 matvec, partial update (pre-ccr)
        float q[MT];
        {
            const float4* qp4 = reinterpret_cast<const float4*>(&s_q[kh][gR][0]);
            float4 qx = qp4[0], qy = qp4[1];
            float2 qz = reinterpret_cast<const float2*>(qp4)[4];
            q[0] = qx.x; q[1] = qx.y; q[2] = qx.z; q[3] = qx.w;
            q[4] = qy.x; q[5] = qy.y; q[6] = qy.z; q[7] = qy.w;
            q[8] = qz.x; q[9] = qz.y;
        }
        float y1[MT];
        #pragma unroll
        for (int t = 0; t < MT; t++) y1[t] = cmpl ? q[t] : 0.f;
        unsigned mm = lmask;
        while (mm) {
            int b = __ffs(mm) - 1;
            mm &= mm - 1;
            const float4* rb4 = reinterpret_cast<const float4*>(&s_T[kh][gR][b][0]);
            float4 ra = rb4[0], rb = rb4[1];
            float2 rc = reinterpret_cast<const float2*>(rb4)[4];
            y1[0] += sgn * ra.x; y1[1] += sgn * ra.y; y1[2] += sgn * ra.z; y1[3] += sgn * ra.w;
            y1[4] += sgn * rb.x; y1[5] += sgn * rb.y; y1[6] += sgn * rb.z; y1[7] += sgn * rb.w;
            y1[8] += sgn * rc.x; y1[9] += sgn * rc.y;
        }

        // y2 matvec: C2 symmetric -> y2[s] = sum_t y1[t]*C2[t][s], s-contiguous.
        // Operand pairs built from SCALAR loads (uniform addr -> SGPR pair);
        // y1t broadcast -> candidate for v_pk_fma_f32. Worst case: 2x v_fmac
        // with SGPR src = exactly r13 codegen.
        {
            v2f y2v[5];
            #pragma unroll
            for (int sv = 0; sv < 5; sv++) y2v[sv] = (v2f){0.f, 0.f};
            #pragma unroll
            for (int t = 0; t < MT; t++) {
                const float y1t = y1[t];
                const v2f yb = {y1t, y1t};
                const float* crow = c2p + t * MT;
                #pragma unroll
                for (int sv = 0; sv < 5; sv++) {
                    v2f c;
                    c.x = crow[2 * sv];
                    c.y = crow[2 * sv + 1];
                    y2v[sv] += yb * c;
                }
            }
            #pragma unroll
            for (int sv = 0; sv < 5; sv++) {
                lt[2 * sv]     += tgl * y2v[sv].x - Mc[2 * sv];
                lt[2 * sv + 1] += tgl * y2v[sv].y - Mc[2 * sv + 1];
            }
        }
        __syncthreads();                         // (3) cc visible

        {
            const float4* cp = reinterpret_cast<const float4*>(&s_cc[kh][gR][0]);
            float4 ca = cp[0], cb = cp[1];
            float2 c2 = reinterpret_cast<const float2*>(cp)[4];
            lt[0] -= ca.x; lt[1] -= ca.y; lt[2] -= ca.z; lt[3] -= ca.w;
            lt[4] -= cb.x; lt[5] -= cb.y; lt[6] -= cb.z; lt[7] -= cb.w;
            lt[8] -= c2.x; lt[9] -= c2.y;
        }
    }

    if (cvalid) {
        int nOut = nb + cn;
        if (nOut < NN)
            out[(size_t)nOut * (NTPL * MT) + (kb + ck) * MT + ct] = qa;
    }
}

extern "C" void kernel_launch(void* const* d_in, const int* in_sizes, int n_in,
                              void* d_out, int out_size, void* d_ws, size_t ws_size,
                              hipStream_t stream) {
    const float* x      = (const float*)d_in[0];
    const int*   eidx   = (const int*)d_in[1];
    const float* tmpl   = (const float*)d_in[2];
    const float* tmplf  = (const float*)d_in[3];
    const float* alpha0 = (const float*)d_in[4];
    float*       outp   = (float*)d_out;

    const int* dst = eidx + NN * DEG;
    float* G = (float*)d_ws;
    const size_t gbytes = (size_t)NN * NTPL * MT * sizeof(float);
    int useG = (ws_size >= gbytes) ? 1 : 0;

    if (useG)
        gcost_kernel<<<dim3((NN + GBN - 1) / GBN, NTPL * MT / GBK), dim3(128), 0, stream>>>(
            x, tmplf, alpha0, G);

    srfgw_kernel<<<dim3((NN + NPB - 1) / NPB, NTPL / KPB), dim3(BS), 0, stream>>>(
        x, dst, tmpl, tmplf, alpha0, G, useG, outp);
}